// Round 1
// baseline (226.626 us; speedup 1.0000x reference)
//
#include <hip/hip_runtime.h>
#include <stdint.h>

typedef short bf16x8 __attribute__((ext_vector_type(8)));
typedef float f32x4 __attribute__((ext_vector_type(4)));

#define T_M   512
#define ML_   1536
#define LSEQ  1568
#define NHEAD 12
#define DHEAD 64
#define CDIM  768
#define NSEG  8
#define MROWS 6272  // B*L

__device__ __forceinline__ unsigned short f2bf(float f) {
  unsigned u = __float_as_uint(f);
  u += 0x7fffu + ((u >> 16) & 1u);  // RNE
  return (unsigned short)(u >> 16);
}

__device__ __forceinline__ void gll16(const void* g, void* l) {
  auto* lp = reinterpret_cast<__attribute__((address_space(3))) unsigned int*>(
      reinterpret_cast<uintptr_t>(l));
  auto* gp = reinterpret_cast<const __attribute__((address_space(1))) unsigned int*>(
      reinterpret_cast<uintptr_t>(g));
  __builtin_amdgcn_global_load_lds(gp, lp, 16, 0, 0);
}

__device__ __forceinline__ f32x4 mfma16(bf16x8 a, bf16x8 b, f32x4 c) {
  return __builtin_amdgcn_mfma_f32_16x16x32_bf16(a, b, c, 0, 0, 0);
}

__global__ __launch_bounds__(256) void cvt_kernel(const float* __restrict__ in,
                                                  unsigned short* __restrict__ out, int n4) {
  int i = blockIdx.x * 256 + threadIdx.x;
  if (i >= n4) return;
  float4 v = reinterpret_cast<const float4*>(in)[i];
  ushort4 o;
  o.x = f2bf(v.x); o.y = f2bf(v.y); o.z = f2bf(v.z); o.w = f2bf(v.w);
  reinterpret_cast<ushort4*>(out)[i] = o;
}

// C[m,n] = sum_k A[m,k]*Bw[n,k] + bias[n].  A:[M,K] bf16, Bw:[N,K] bf16 (row-major).
// BM=BN=128, BK=64; 4 waves (2x2), each wave owns 64x64.
// LDS layout: logical (r,c-byte) lives at r*128 + (cbyte ^ ((r&7)<<4))  (XOR swizzle,
// applied as inverse-swizzled global SOURCE for global_load_lds + swizzled ds_read).
template <int OUT_BF16>
__global__ __launch_bounds__(256) void gemm_bt(const unsigned short* __restrict__ A,
                                               const unsigned short* __restrict__ Bw,
                                               const float* __restrict__ bias,
                                               void* __restrict__ Cout,
                                               int M, int N, int K) {
  __shared__ char smem[32768];  // A tile [0,16K), B tile [16K,32K)
  const int tid = threadIdx.x;
  const int lane = tid & 63;
  const int w = tid >> 6;
  const int m0 = blockIdx.y * 128, n0 = blockIdx.x * 128;
  const int wr = (w >> 1) * 64, wc = (w & 1) * 64;

  unsigned gaoff[4], gboff[4];
#pragma unroll
  for (int it = 0; it < 4; ++it) {
    int off = it * 4096 + tid * 16;        // linear LDS byte offset this thread fills
    int r = off >> 7;                      // row 0..127
    int cb = (off & 127) ^ ((r & 7) << 4); // inverse swizzle -> logical k-byte
    gaoff[it] = (unsigned)((m0 + r) * K * 2 + cb);
    gboff[it] = (unsigned)((n0 + r) * K * 2 + cb);
  }
  const char* Ab = (const char*)A;
  const char* Bb = (const char*)Bw;

  f32x4 acc[4][4] = {};

  for (int ks = 0; ks < K; ks += 64) {
    __syncthreads();
#pragma unroll
    for (int it = 0; it < 4; ++it) {
      gll16(Ab + gaoff[it] + ks * 2, smem + it * 4096 + tid * 16);
      gll16(Bb + gboff[it] + ks * 2, smem + 16384 + it * 4096 + tid * 16);
    }
    __syncthreads();
#pragma unroll
    for (int kk = 0; kk < 2; ++kk) {
      const int cb = kk * 64 + (lane >> 4) * 16;
      bf16x8 av[4], bv[4];
#pragma unroll
      for (int mi = 0; mi < 4; ++mi) {
        int r = wr + mi * 16 + (lane & 15);
        av[mi] = *reinterpret_cast<const bf16x8*>(smem + r * 128 + (cb ^ ((r & 7) << 4)));
      }
#pragma unroll
      for (int ni = 0; ni < 4; ++ni) {
        int r = wc + ni * 16 + (lane & 15);
        bv[ni] = *reinterpret_cast<const bf16x8*>(smem + 16384 + r * 128 + (cb ^ ((r & 7) << 4)));
      }
#pragma unroll
      for (int mi = 0; mi < 4; ++mi)
#pragma unroll
        for (int ni = 0; ni < 4; ++ni)
          acc[mi][ni] = mfma16(av[mi], bv[ni], acc[mi][ni]);
    }
  }

#pragma unroll
  for (int mi = 0; mi < 4; ++mi) {
#pragma unroll
    for (int ni = 0; ni < 4; ++ni) {
      int col = n0 + wc + ni * 16 + (lane & 15);
      float bs = bias[col];
#pragma unroll
      for (int reg = 0; reg < 4; ++reg) {
        int row = m0 + wr + mi * 16 + (lane >> 4) * 4 + reg;
        float v = acc[mi][ni][reg] + bs;
        if (OUT_BF16)
          ((unsigned short*)Cout)[(size_t)row * N + col] = f2bf(v);
        else
          ((float*)Cout)[(size_t)row * N + col] = v;
      }
    }
  }
}

// Flash attention with cross-conditional mask.
// Grid: (qtile 0..24, head 0..11, batch 0..3). 4 waves x 16 q-rows, KV tile = 64.
__global__ __launch_bounds__(256) void attn_kernel(const unsigned short* __restrict__ qb,
                                                   const unsigned short* __restrict__ kb,
                                                   const unsigned short* __restrict__ vb,
                                                   unsigned short* __restrict__ yb,
                                                   const int* __restrict__ seg_s,
                                                   const int* __restrict__ seg_e) {
  __shared__ char vt[8192];        // V^T tile [64 d][64 j] bf16, XOR-swizzled
  __shared__ char plds[4][2048];   // per-wave P [16][64] bf16, XOR-swizzled
  __shared__ int ssh[NSEG], seh[NSEG];
  const int tid = threadIdx.x;
  const int lane = tid & 63;
  const int w = tid >> 6;
  const int lh = lane & 15, lg = lane >> 4;
  const int qt = blockIdx.x;
  const int h = blockIdx.y;
  const int b = blockIdx.z;

  if (tid < NSEG) { ssh[tid] = seg_s[b * NSEG + tid]; seh[tid] = seg_e[b * NSEG + tid]; }

  const int rb_q = qt >> 3;   // 0,1,2 = motion blocks; 3 = text tile
  const int qtl = qt & 7;

  // Q fragments held in registers for the whole loop (A operand: row=lh, k=lg*8..)
  int qr = qt * 64 + w * 16 + lh;
  if (qr >= LSEQ) qr = LSEQ - 1;
  const unsigned short* qp = qb + ((size_t)(b * LSEQ + qr) * CDIM + h * DHEAD + lg * 8);
  const bf16x8 qf0 = *reinterpret_cast<const bf16x8*>(qp);
  const bf16x8 qf1 = *reinterpret_cast<const bf16x8*>(qp + 32);

  f32x4 o[4] = {};
  float m_run[4] = {-1e30f, -1e30f, -1e30f, -1e30f};
  float l_run[4] = {0.f, 0.f, 0.f, 0.f};

  const int vj = tid >> 2;          // j row this thread stages
  const int vd0 = (tid & 3) * 16;   // d range start
  char* pw = plds[w];

  __syncthreads();  // ssh/seh visible

  for (int kt = 0; kt < 25; ++kt) {
    bool inc;
    if (rb_q >= 3) inc = true;
    else if (rb_q == 0) inc = (kt <= qtl);
    else inc = (kt == 24) || ((kt & 7) <= qtl);
    if (!inc) continue;  // block-uniform skip

    __syncthreads();  // protect vt/plds reuse from previous iteration's reads

    // stage V^T (swizzled): vt[d][j]
    {
      int vr = kt * 64 + vj;
      if (vr >= LSEQ) vr = LSEQ - 1;
      const unsigned short* vp = vb + ((size_t)(b * LSEQ + vr) * CDIM + h * DHEAD + vd0);
      unsigned short tmp[16] __attribute__((aligned(16)));
      *reinterpret_cast<uint4*>(tmp) = *reinterpret_cast<const uint4*>(vp);
      *reinterpret_cast<uint4*>(tmp + 8) = *reinterpret_cast<const uint4*>(vp + 8);
#pragma unroll
      for (int e = 0; e < 16; ++e) {
        int d = vd0 + e;
        *reinterpret_cast<unsigned short*>(vt + d * 128 + ((vj * 2) ^ ((d & 7) << 4))) = tmp[e];
      }
    }

    // S = Q K^T  (K fragments direct from global; all 4 waves share -> L1 hits)
    f32x4 s[4];
#pragma unroll
    for (int nt = 0; nt < 4; ++nt) {
      int kr = kt * 64 + nt * 16 + lh;
      if (kr >= LSEQ) kr = LSEQ - 1;
      const unsigned short* kp = kb + ((size_t)(b * LSEQ + kr) * CDIM + h * DHEAD + lg * 8);
      bf16x8 k0 = *reinterpret_cast<const bf16x8*>(kp);
      bf16x8 k1 = *reinterpret_cast<const bf16x8*>(kp + 32);
      f32x4 z = {};
      z = mfma16(qf0, k0, z);
      z = mfma16(qf1, k1, z);
      s[nt] = z;
    }

    // mask + scale (mask math only on partial tiles)
    const bool partial = (kt == 24) || ((rb_q < 3) && ((kt & 7) == qtl));
    if (!partial) {
#pragma unroll
      for (int nt = 0; nt < 4; ++nt)
#pragma unroll
        for (int reg = 0; reg < 4; ++reg) s[nt][reg] *= 0.125f;
    } else {
#pragma unroll
      for (int reg = 0; reg < 4; ++reg) {
        int r = qt * 64 + w * 16 + lg * 4 + reg;
        int f = r & 511;
#pragma unroll
        for (int nt = 0; nt < 4; ++nt) {
          int c = kt * 64 + nt * 16 + lh;
          bool ok;
          if (rb_q >= 3) {
            ok = (c < LSEQ);  // text rows attend everything valid
          } else if (kt < 24) {
            int cbk = kt >> 3;           // uniform col-block per kt
            int g = c - cbk * 512;
            bool strict = (rb_q == 1) ? (cbk != 0) : (cbk == 2);
            ok = strict ? (g < f) : (g <= f);
          } else {
            int tc = c - ML_;            // text columns
            int j = tc >> 3, i = tc & 7;
            bool st = (rb_q == 1) ? (j != 1) : (j != 0);
            ok = (tc < 32) && st && (f >= ssh[i]) && (f < seh[i]);
          }
          s[nt][reg] = ok ? s[nt][reg] * 0.125f : -1e30f;
        }
      }
    }

    // online softmax (16-lane row reductions; rows replicated across the quarter-wave)
    float fac[4];
#pragma unroll
    for (int reg = 0; reg < 4; ++reg) {
      float mt = fmaxf(fmaxf(s[0][reg], s[1][reg]), fmaxf(s[2][reg], s[3][reg]));
#pragma unroll
      for (int off = 1; off < 16; off <<= 1) mt = fmaxf(mt, __shfl_xor(mt, off));
      float mn = fmaxf(m_run[reg], mt);
      float fc = __expf(m_run[reg] - mn);
      float ps = 0.f;
#pragma unroll
      for (int nt = 0; nt < 4; ++nt) {
        float p = __expf(s[nt][reg] - mn);
        s[nt][reg] = p;
        ps += p;
      }
#pragma unroll
      for (int off = 1; off < 16; off <<= 1) ps += __shfl_xor(ps, off);
      l_run[reg] = l_run[reg] * fc + ps;
      m_run[reg] = mn;
      fac[reg] = fc;
    }
#pragma unroll
    for (int dt = 0; dt < 4; ++dt)
#pragma unroll
      for (int reg = 0; reg < 4; ++reg) o[dt][reg] *= fac[reg];

    // write P (bf16, swizzled) into this wave's region
#pragma unroll
    for (int reg = 0; reg < 4; ++reg) {
      int row = lg * 4 + reg;
      int swz = (row & 7) << 4;
#pragma unroll
      for (int nt = 0; nt < 4; ++nt) {
        int cbyte = (nt * 16 + lh) * 2;
        *reinterpret_cast<unsigned short*>(pw + row * 128 + (cbyte ^ swz)) = f2bf(s[nt][reg]);
      }
    }

    __syncthreads();  // V^T staged + P visible

    // O += P @ V   (A = P rows, B = V^T rows: both 8-contiguous-j reads)
#pragma unroll
    for (int jc = 0; jc < 2; ++jc) {
      int cbj = (jc * 32 + lg * 8) * 2;
      bf16x8 pf = *reinterpret_cast<const bf16x8*>(pw + lh * 128 + (cbj ^ ((lh & 7) << 4)));
#pragma unroll
      for (int dt = 0; dt < 4; ++dt) {
        int d = dt * 16 + lh;
        bf16x8 vf = *reinterpret_cast<const bf16x8*>(vt + d * 128 + (cbj ^ ((d & 7) << 4)));
        o[dt] = mfma16(pf, vf, o[dt]);
      }
    }
  }

  // normalize + write y (bf16)
#pragma unroll
  for (int reg = 0; reg < 4; ++reg) {
    int r = qt * 64 + w * 16 + lg * 4 + reg;
    if (r >= LSEQ) continue;
    float inv = 1.0f / l_run[reg];
#pragma unroll
    for (int dt = 0; dt < 4; ++dt) {
      float v = o[dt][reg] * inv;
      yb[(size_t)(b * LSEQ + r) * CDIM + h * DHEAD + dt * 16 + lh] = f2bf(v);
    }
  }
}

extern "C" void kernel_launch(void* const* d_in, const int* in_sizes, int n_in,
                              void* d_out, int out_size, void* d_ws, size_t ws_size,
                              hipStream_t stream) {
  (void)in_sizes; (void)n_in; (void)out_size;
  const float* x  = (const float*)d_in[0];
  const float* Wq = (const float*)d_in[1];
  const float* bq = (const float*)d_in[2];
  const float* Wk = (const float*)d_in[3];
  const float* bk = (const float*)d_in[4];
  const float* Wv = (const float*)d_in[5];
  const float* bv = (const float*)d_in[6];
  const float* Wp = (const float*)d_in[7];
  const float* bp = (const float*)d_in[8];
  const int* seg_s = (const int*)d_in[9];
  const int* seg_e = (const int*)d_in[10];

  const size_t NX = (size_t)MROWS * CDIM;  // 4,816,896
  const size_t NW = (size_t)CDIM * CDIM;   // 589,824
  const size_t need = (NX * 5 + NW * 4) * 2;
  if (ws_size < need) return;  // leaves d_out unwritten -> visible failure, no corruption

  unsigned short* xb   = (unsigned short*)d_ws;
  unsigned short* wqb  = xb + NX;
  unsigned short* wkb  = wqb + NW;
  unsigned short* wvb  = wkb + NW;
  unsigned short* wpb  = wvb + NW;
  unsigned short* qbuf = wpb + NW;
  unsigned short* kbuf = qbuf + NX;
  unsigned short* vbuf = kbuf + NX;
  unsigned short* ybuf = vbuf + NX;

  // f32 -> bf16 conversions
  {
    int n4 = (int)(NX / 4);
    cvt_kernel<<<(n4 + 255) / 256, 256, 0, stream>>>(x, xb, n4);
    int w4 = (int)(NW / 4);
    cvt_kernel<<<(w4 + 255) / 256, 256, 0, stream>>>(Wq, wqb, w4);
    cvt_kernel<<<(w4 + 255) / 256, 256, 0, stream>>>(Wk, wkb, w4);
    cvt_kernel<<<(w4 + 255) / 256, 256, 0, stream>>>(Wv, wvb, w4);
    cvt_kernel<<<(w4 + 255) / 256, 256, 0, stream>>>(Wp, wpb, w4);
  }

  dim3 gg(CDIM / 128, MROWS / 128);  // (6, 49)
  gemm_bt<1><<<gg, 256, 0, stream>>>(xb, wqb, bq, qbuf, MROWS, CDIM, CDIM);
  gemm_bt<1><<<gg, 256, 0, stream>>>(xb, wkb, bk, kbuf, MROWS, CDIM, CDIM);
  gemm_bt<1><<<gg, 256, 0, stream>>>(xb, wvb, bv, vbuf, MROWS, CDIM, CDIM);

  dim3 ga(25, NHEAD, 4);
  attn_kernel<<<ga, 256, 0, stream>>>(qbuf, kbuf, vbuf, ybuf, seg_s, seg_e);

  gemm_bt<0><<<gg, 256, 0, stream>>>(ybuf, wpb, bp, d_out, MROWS, CDIM, CDIM);
}

// Round 2
// 204.413 us; speedup vs baseline: 1.1087x; 1.1087x over previous
//
#include <hip/hip_runtime.h>
#include <stdint.h>

typedef short bf16x8 __attribute__((ext_vector_type(8)));
typedef float f32x4 __attribute__((ext_vector_type(4)));

#define T_M   512
#define ML_   1536
#define LSEQ  1568
#define NHEAD 12
#define DHEAD 64
#define CDIM  768
#define NSEG  8
#define MROWS 6272  // B*L
#define CQK   1536  // q|k concat row stride
#define VTN   6272  // vt row length

__device__ __forceinline__ unsigned short f2bf(float f) {
  unsigned u = __float_as_uint(f);
  u += 0x7fffu + ((u >> 16) & 1u);  // RNE
  return (unsigned short)(u >> 16);
}

__device__ __forceinline__ void gll16(const void* g, void* l) {
  auto* lp = reinterpret_cast<__attribute__((address_space(3))) unsigned int*>(
      reinterpret_cast<uintptr_t>(l));
  auto* gp = reinterpret_cast<const __attribute__((address_space(1))) unsigned int*>(
      reinterpret_cast<uintptr_t>(g));
  __builtin_amdgcn_global_load_lds(gp, lp, 16, 0, 0);
}

__device__ __forceinline__ f32x4 mfma16(bf16x8 a, bf16x8 b, f32x4 c) {
  return __builtin_amdgcn_mfma_f32_16x16x32_bf16(a, b, c, 0, 0, 0);
}

__global__ __launch_bounds__(256) void cvt_kernel(const float* __restrict__ in,
                                                  unsigned short* __restrict__ out, int n4) {
  int i = blockIdx.x * 256 + threadIdx.x;
  if (i >= n4) return;
  float4 v = reinterpret_cast<const float4*>(in)[i];
  ushort4 o;
  o.x = f2bf(v.x); o.y = f2bf(v.y); o.z = f2bf(v.z); o.w = f2bf(v.w);
  reinterpret_cast<ushort4*>(out)[i] = o;
}

// C[m,n] = sum_k A[m,k]*Bw[n,k] + bias.  A:[M,K] bf16, Bw:[N,K] bf16 (row-major).
// BM=BN=128, BK=64; 4 waves (2x2), each wave owns 64x64. XOR-swizzled LDS
// (inverse-swizzled global source for global_load_lds + swizzled ds_read).
// BIAS_ROW: bias indexed by output row (for the V^T producer); else by col with
// a split (bias0 for col<bsplit, bias1 above).
template <int OUT_BF16, int BIAS_ROW>
__global__ __launch_bounds__(256) void gemm_bt(const unsigned short* __restrict__ A,
                                               const unsigned short* __restrict__ Bw,
                                               const float* __restrict__ bias0,
                                               const float* __restrict__ bias1, int bsplit,
                                               void* __restrict__ Cout,
                                               int M, int N, int K) {
  __shared__ char smem[32768];  // A tile [0,16K), B tile [16K,32K)
  const int tid = threadIdx.x;
  const int lane = tid & 63;
  const int w = tid >> 6;
  const int m0 = blockIdx.y * 128, n0 = blockIdx.x * 128;
  const int wr = (w >> 1) * 64, wc = (w & 1) * 64;

  unsigned gaoff[4], gboff[4];
#pragma unroll
  for (int it = 0; it < 4; ++it) {
    int off = it * 4096 + tid * 16;        // linear LDS byte offset this thread fills
    int r = off >> 7;                      // row 0..127
    int cb = (off & 127) ^ ((r & 7) << 4); // inverse swizzle -> logical k-byte
    gaoff[it] = (unsigned)((m0 + r) * K * 2 + cb);
    gboff[it] = (unsigned)((n0 + r) * K * 2 + cb);
  }
  const char* Ab = (const char*)A;
  const char* Bb = (const char*)Bw;

  f32x4 acc[4][4] = {};

  for (int ks = 0; ks < K; ks += 64) {
    __syncthreads();
#pragma unroll
    for (int it = 0; it < 4; ++it) {
      gll16(Ab + gaoff[it] + ks * 2, smem + it * 4096 + tid * 16);
      gll16(Bb + gboff[it] + ks * 2, smem + 16384 + it * 4096 + tid * 16);
    }
    __syncthreads();
#pragma unroll
    for (int kk = 0; kk < 2; ++kk) {
      const int cb = kk * 64 + (lane >> 4) * 16;
      bf16x8 av[4], bv[4];
#pragma unroll
      for (int mi = 0; mi < 4; ++mi) {
        int r = wr + mi * 16 + (lane & 15);
        av[mi] = *reinterpret_cast<const bf16x8*>(smem + r * 128 + (cb ^ ((r & 7) << 4)));
      }
#pragma unroll
      for (int ni = 0; ni < 4; ++ni) {
        int r = wc + ni * 16 + (lane & 15);
        bv[ni] = *reinterpret_cast<const bf16x8*>(smem + 16384 + r * 128 + (cb ^ ((r & 7) << 4)));
      }
#pragma unroll
      for (int mi = 0; mi < 4; ++mi)
#pragma unroll
        for (int ni = 0; ni < 4; ++ni)
          acc[mi][ni] = mfma16(av[mi], bv[ni], acc[mi][ni]);
    }
  }

#pragma unroll
  for (int mi = 0; mi < 4; ++mi) {
#pragma unroll
    for (int ni = 0; ni < 4; ++ni) {
      int col = n0 + wc + ni * 16 + (lane & 15);
      float bsc = BIAS_ROW ? 0.f : (col < bsplit ? bias0[col] : bias1[col - bsplit]);
#pragma unroll
      for (int reg = 0; reg < 4; ++reg) {
        int row = m0 + wr + mi * 16 + (lane >> 4) * 4 + reg;
        float v = acc[mi][ni][reg] + (BIAS_ROW ? bias0[row] : bsc);
        if (OUT_BF16)
          ((unsigned short*)Cout)[(size_t)row * N + col] = f2bf(v);
        else
          ((float*)Cout)[(size_t)row * N + col] = v;
      }
    }
  }
}

// LPT order of the 100 (qt, subtile) units, descending work (tiles per unit).
__device__ const unsigned char qorder[100] = {
    60, 61, 62, 63, 92, 93, 94, 95, 96, 97, 98, 99,   // w=25
    56, 57, 58, 59, 88, 89, 90, 91,                   // w=22
    52, 53, 54, 55, 84, 85, 86, 87,                   // w=19
    48, 49, 50, 51, 80, 81, 82, 83,                   // w=16
    44, 45, 46, 47, 76, 77, 78, 79,                   // w=13
    40, 41, 42, 43, 72, 73, 74, 75,                   // w=10
    28, 29, 30, 31,                                   // w=8
    36, 37, 38, 39, 68, 69, 70, 71, 24, 25, 26, 27,   // w=7
    20, 21, 22, 23,                                   // w=6
    16, 17, 18, 19,                                   // w=5
    32, 33, 34, 35, 64, 65, 66, 67, 12, 13, 14, 15,   // w=4
    8, 9, 10, 11,                                     // w=3
    4, 5, 6, 7,                                       // w=2
    0, 1, 2, 3};                                      // w=1

// Flash attention, 1 wave per block, no barriers.
// qk: [6272][1536] bf16 (q cols 0..767, k cols 768..1535)
// vt: [768][6272] bf16  (row = h*64+d, col = b*1568+j)
// Grid: (48 bh, 100 rank), 64 threads.
__global__ __launch_bounds__(64) void attn_kernel(const unsigned short* __restrict__ qk,
                                                  const unsigned short* __restrict__ vt,
                                                  unsigned short* __restrict__ yb,
                                                  const int* __restrict__ seg_s,
                                                  const int* __restrict__ seg_e) {
  __shared__ char pw[2048];  // wave-private P [16][64] bf16, XOR-swizzled
  const int lane = threadIdx.x;
  const int lh = lane & 15, lg = lane >> 4;
  const int bh = blockIdx.x;
  const int b = bh / NHEAD, h = bh % NHEAD;
  const int qsub = qorder[blockIdx.y];
  const int qt = qsub >> 2, wsub = qsub & 3;
  const int rb_q = qt >> 3;   // 0,1,2 = motion blocks; 3 = text tile
  const int qtl = qt & 7;

  // Q fragments in registers for the whole loop (A operand: row=lh, k=lg*8..)
  int qr = qt * 64 + wsub * 16 + lh;
  if (qr >= LSEQ) qr = LSEQ - 1;
  const unsigned short* qp = qk + ((size_t)(b * LSEQ + qr) * CQK + h * DHEAD + lg * 8);
  const bf16x8 qf0 = *reinterpret_cast<const bf16x8*>(qp);
  const bf16x8 qf1 = *reinterpret_cast<const bf16x8*>(qp + 32);

  const unsigned short* kbase = qk + 768 + h * DHEAD + lg * 8;           // + row*CQK
  const unsigned short* vbase = vt + (size_t)(h * DHEAD + lh) * VTN + (size_t)b * LSEQ;

  f32x4 o[4] = {};
  float m_run[4] = {-1e30f, -1e30f, -1e30f, -1e30f};
  float l_run[4] = {0.f, 0.f, 0.f, 0.f};

  for (int kt = 0; kt < 25; ++kt) {
    bool inc;
    if (rb_q >= 3) inc = true;
    else if (rb_q == 0) inc = (kt <= qtl);
    else inc = (kt == 24) || ((kt & 7) <= qtl);
    if (!inc) continue;  // block-uniform skip

    // S = Q K^T  (K fragments direct from global)
    f32x4 s[4];
#pragma unroll
    for (int nt = 0; nt < 4; ++nt) {
      int kr = kt * 64 + nt * 16 + lh;
      if (kr >= LSEQ) kr = LSEQ - 1;
      const unsigned short* kp = kbase + (size_t)(b * LSEQ + kr) * CQK;
      bf16x8 k0 = *reinterpret_cast<const bf16x8*>(kp);
      bf16x8 k1 = *reinterpret_cast<const bf16x8*>(kp + 32);
      f32x4 z = {};
      z = mfma16(qf0, k0, z);
      z = mfma16(qf1, k1, z);
      s[nt] = z;
    }

    // mask + scale (mask math only on partial tiles)
    const bool partial = (kt == 24) || ((rb_q < 3) && ((kt & 7) == qtl));
    if (!partial) {
#pragma unroll
      for (int nt = 0; nt < 4; ++nt)
#pragma unroll
        for (int reg = 0; reg < 4; ++reg) s[nt][reg] *= 0.125f;
    } else {
#pragma unroll
      for (int reg = 0; reg < 4; ++reg) {
        int r = qt * 64 + wsub * 16 + lg * 4 + reg;
        int f = r & 511;
#pragma unroll
        for (int nt = 0; nt < 4; ++nt) {
          int c = kt * 64 + nt * 16 + lh;
          bool ok;
          if (rb_q >= 3) {
            ok = (c < LSEQ);  // text rows attend everything valid
          } else if (kt < 24) {
            int cbk = kt >> 3;           // uniform col-block per kt
            int g = c - cbk * 512;
            bool strict = (rb_q == 1) ? (cbk != 0) : (cbk == 2);
            ok = strict ? (g < f) : (g <= f);
          } else {
            int tc = c - ML_;            // text columns
            int j = tc >> 3, i = tc & 7;
            bool st = (rb_q == 1) ? (j != 1) : (j != 0);
            ok = (tc < 32) && st && (f >= seg_s[b * NSEG + i]) && (f < seg_e[b * NSEG + i]);
          }
          s[nt][reg] = ok ? s[nt][reg] * 0.125f : -1e30f;
        }
      }
    }

    // online softmax (16-lane row reductions)
    float fac[4];
#pragma unroll
    for (int reg = 0; reg < 4; ++reg) {
      float mt = fmaxf(fmaxf(s[0][reg], s[1][reg]), fmaxf(s[2][reg], s[3][reg]));
#pragma unroll
      for (int off = 1; off < 16; off <<= 1) mt = fmaxf(mt, __shfl_xor(mt, off));
      float mn = fmaxf(m_run[reg], mt);
      float fc = __expf(m_run[reg] - mn);
      float ps = 0.f;
#pragma unroll
      for (int nt = 0; nt < 4; ++nt) {
        float p = __expf(s[nt][reg] - mn);
        s[nt][reg] = p;
        ps += p;
      }
#pragma unroll
      for (int off = 1; off < 16; off <<= 1) ps += __shfl_xor(ps, off);
      l_run[reg] = l_run[reg] * fc + ps;
      m_run[reg] = mn;
      fac[reg] = fc;
    }
#pragma unroll
    for (int dt = 0; dt < 4; ++dt)
#pragma unroll
      for (int reg = 0; reg < 4; ++reg) o[dt][reg] *= fac[reg];

    // write P (bf16, swizzled) — wave-private, no barrier needed
#pragma unroll
    for (int reg = 0; reg < 4; ++reg) {
      int row = lg * 4 + reg;
      int swz = (row & 7) << 4;
#pragma unroll
      for (int nt = 0; nt < 4; ++nt) {
        int cbyte = (nt * 16 + lh) * 2;
        *reinterpret_cast<unsigned short*>(pw + row * 128 + (cbyte ^ swz)) = f2bf(s[nt][reg]);
      }
    }

    // O += P @ V   (P from wave-private LDS, V^T fragments direct from global)
#pragma unroll
    for (int jc = 0; jc < 2; ++jc) {
      int cbj = (jc * 32 + lg * 8) * 2;
      bf16x8 pf = *reinterpret_cast<const bf16x8*>(pw + lh * 128 + (cbj ^ ((lh & 7) << 4)));
#pragma unroll
      for (int dt = 0; dt < 4; ++dt) {
        const unsigned short* vp = vbase + (size_t)(dt * 16) * VTN + kt * 64 + jc * 32 + lg * 8;
        bf16x8 vf = *reinterpret_cast<const bf16x8*>(vp);
        o[dt] = mfma16(pf, vf, o[dt]);
      }
    }
  }

  // normalize + write y (bf16)
#pragma unroll
  for (int reg = 0; reg < 4; ++reg) {
    int r = qt * 64 + wsub * 16 + lg * 4 + reg;
    if (r >= LSEQ) continue;
    float inv = 1.0f / l_run[reg];
#pragma unroll
    for (int dt = 0; dt < 4; ++dt) {
      float v = o[dt][reg] * inv;
      yb[(size_t)(b * LSEQ + r) * CDIM + h * DHEAD + dt * 16 + lh] = f2bf(v);
    }
  }
}

extern "C" void kernel_launch(void* const* d_in, const int* in_sizes, int n_in,
                              void* d_out, int out_size, void* d_ws, size_t ws_size,
                              hipStream_t stream) {
  (void)in_sizes; (void)n_in; (void)out_size;
  const float* x  = (const float*)d_in[0];
  const float* Wq = (const float*)d_in[1];
  const float* bq = (const float*)d_in[2];
  const float* Wk = (const float*)d_in[3];
  const float* bk = (const float*)d_in[4];
  const float* Wv = (const float*)d_in[5];
  const float* bv = (const float*)d_in[6];
  const float* Wp = (const float*)d_in[7];
  const float* bp = (const float*)d_in[8];
  const int* seg_s = (const int*)d_in[9];
  const int* seg_e = (const int*)d_in[10];

  const size_t NX = (size_t)MROWS * CDIM;  // 4,816,896
  const size_t NW = (size_t)CDIM * CDIM;   // 589,824
  const size_t need = (NX * 5 + NW * 4) * 2;
  if (ws_size < need) return;

  unsigned short* xb    = (unsigned short*)d_ws;
  unsigned short* wqkb  = xb + NX;          // [1536][768] (Wq rows, then Wk rows)
  unsigned short* wvb   = wqkb + 2 * NW;
  unsigned short* wpb   = wvb + NW;
  unsigned short* qkbuf = wpb + NW;         // [6272][1536]
  unsigned short* vtbuf = qkbuf + 2 * NX;   // [768][6272]
  unsigned short* ybuf  = vtbuf + NX;       // MUST follow vtbuf (tiny masked OOB reads land here)

  // f32 -> bf16 conversions
  {
    int n4 = (int)(NX / 4);
    cvt_kernel<<<(n4 + 255) / 256, 256, 0, stream>>>(x, xb, n4);
    int w4 = (int)(NW / 4);
    cvt_kernel<<<(w4 + 255) / 256, 256, 0, stream>>>(Wq, wqkb, w4);
    cvt_kernel<<<(w4 + 255) / 256, 256, 0, stream>>>(Wk, wqkb + NW, w4);
    cvt_kernel<<<(w4 + 255) / 256, 256, 0, stream>>>(Wv, wvb, w4);
    cvt_kernel<<<(w4 + 255) / 256, 256, 0, stream>>>(Wp, wpb, w4);
  }

  // Q|K fused projection: [6272][1536]
  gemm_bt<1, 0><<<dim3(CQK / 128, MROWS / 128), 256, 0, stream>>>(
      xb, wqkb, bq, bk, 768, qkbuf, MROWS, CQK, CDIM);
  // V^T directly via swapped operands: vt[i][m] = sum_k Wv[i,k] x[m,k] + bv[i]
  gemm_bt<1, 1><<<dim3(MROWS / 128, CDIM / 128), 256, 0, stream>>>(
      wvb, xb, bv, bv, 0, vtbuf, CDIM, MROWS, CDIM);

  attn_kernel<<<dim3(48, 100), 64, 0, stream>>>(qkbuf, vtbuf, ybuf, seg_s, seg_e);

  gemm_bt<0, 0><<<dim3(CDIM / 128, MROWS / 128), 256, 0, stream>>>(
      ybuf, wpb, bp, bp, 1 << 30, d_out, MROWS, CDIM, CDIM);
}